// Round 14
// baseline (146.827 us; speedup 1.0000x reference)
//
#include <hip/hip_runtime.h>
#include <hip/hip_bf16.h>

typedef unsigned short u16;
typedef unsigned int u32;
typedef __bf16 bf16x8 __attribute__((ext_vector_type(8)));
typedef float f32x4 __attribute__((ext_vector_type(4)));
typedef unsigned int u32x4 __attribute__((ext_vector_type(4)));
typedef unsigned int u32x2 __attribute__((ext_vector_type(2)));

#define NN 512
#define LL 40
#define DD 128
#define OO 256
#define KK 9
#define MHCL 34
#define TT 32
#define PSTR 136   // pept LDS row stride (u16)
#define KDSTR 72   // fallback kernel only
#define WPADL 64   // padded l-dim in preconverted W

#define PEPT_U16 (LL * PSTR)    // 5440 u16 = 10880 B
#define KS_U16   (32 * KDSTR)   // fallback only
#define EX_U16   1024           // per-wave exchange: 64 lanes x 8 f32 = 2048 B

__device__ __forceinline__ u16 f2bf(float x) {
    unsigned int u = __builtin_bit_cast(unsigned int, x);
    u = (u + 0x7FFFu + ((u >> 16) & 1u)) >> 16;
    return (u16)u;
}
__device__ __forceinline__ u32 pk2(float a, float b) {
    __hip_bfloat162 h = __float22bfloat162_rn(make_float2(a, b)); // x = low half
    u32 r;
    __builtin_memcpy(&r, &h, 4);
    return r;
}
__device__ __forceinline__ bf16x8 ld8(const u16* p) {   // LDS or global, 16B
    u32x4 r;
    __builtin_memcpy(&r, __builtin_assume_aligned(p, 16), 16);
    return __builtin_bit_cast(bf16x8, r);
}
__device__ __forceinline__ f32x4 mfma16(bf16x8 a, bf16x8 b, f32x4 c) {
    return __builtin_amdgcn_mfma_f32_16x16x32_bf16(a, b, c, 0, 0, 0);
}

// fused prologue: W fp32 [O][K][34] -> bf16 [O][K][64] padded, AND
// pept fp32 [N][L][D] -> bf16 same layout. One dispatch.
__global__ void cvt_all(const float* __restrict__ wgt, const float* __restrict__ pept,
                        u32* __restrict__ wp, u32* __restrict__ pp) {
    int i = blockIdx.x * 256 + threadIdx.x;
    const int WN = OO * KK * (WPADL / 2);            // 36864
    if (i < WN) {
        int o = i / (KK * (WPADL / 2));
        int r = i - o * (KK * (WPADL / 2));
        int k = r >> 5;
        int lp = (r & 31) << 1;
        const float* src = wgt + ((size_t)o * KK + k) * MHCL;
        float a = (lp     < MHCL) ? src[lp]     : 0.f;
        float b = (lp + 1 < MHCL) ? src[lp + 1] : 0.f;
        wp[i] = pk2(a, b);
    } else {
        size_t j = (size_t)(i - WN);
        if (j < (size_t)NN * LL * DD / 2)
            pp[j] = pk2(pept[2 * j], pept[2 * j + 1]);
    }
}

// R14: QUARTER-TILE waves to cross the <=64-VGPR occupancy step. R13 null
// (in-reg kern gained only 1.3us) killed the LDS-RAW theory; the arithmetic
// re-derive shows 412 TF = 16% of peak with MfmaUtil 22% and waves/SIMD
// pinned at 4 by unified VGPR ~76 (steps at 64/128/256). Per-wave tile
// shrinks to (16 o' x 32 d): mA 16 + wB 8 + kc 4 + acc 8 + ap 8 ~= 58 regs
// -> launch_bounds(256,8) pins cap at exactly 64 -> 8 waves/SIMD. Same total
// math (wave-tasks partition o x d; kern computed once per element).
// In-register kern kept: d(di, m=4q+r) = dq*32 + 8q + 4di + r (bijective on
// the quarter) makes stage1's packed C regs be stage2's B-frag directly.
// DECLARED RISK: cap==64 vs demand ~58 is a thin margin. Tripwire: WRITE
// >25MB or dur>=100us = spill -> next round relaxes to (256,4).
__global__ __launch_bounds__(256, 8)
void iconv_fast(const float* __restrict__ mhc,
                const u16* __restrict__ wp,
                const u16* __restrict__ pb,
                const float* __restrict__ bias,
                float* __restrict__ out)
{
    // LDS 17024 B: pept[40][136] | 3 x wave-exchange f32[64][8]
    __shared__ __align__(16) u16 s_mem[PEPT_U16 + 3 * EX_U16];

    const int tid  = threadIdx.x;
    const int dq   = tid >> 6;      // wave = d-quarter owner: d in [dq*32, dq*32+32)
    const int lane = tid & 63;
    const int quad = lane >> 4;
    const int l16  = lane & 15;

    const int n  = blockIdx.x >> 4;     // 16 blocks per sample
    const int oc = blockIdx.x & 15;     // o16-chunk index
    const int obase = oc * 16;          // block's 16 o-columns

    u16* const s_pept = s_mem;

    auto loadW = [&](int k, bf16x8 wF[2]) {
        const u16* wr = wp + ((size_t)(obase + l16) * KK + k) * WPADL;
        u32x4 r0, r1;
        __builtin_memcpy(&r0, __builtin_assume_aligned(wr + quad * 8, 16), 16);
        __builtin_memcpy(&r1, __builtin_assume_aligned(wr + 32 + quad * 8, 16), 16);
        wF[0] = __builtin_bit_cast(bf16x8, r0);
        wF[1] = __builtin_bit_cast(bf16x8, r1);
    };

    // first W fragments in flight under the prologue
    bf16x8 wB[2];
    loadW(0, wB);

    // ---- mA DIRECT from global fp32, PERMUTED d-rows within the quarter ----
    // A-frag row m (= l16) of sub-matrix di (di in {0,1}) maps to
    //   d = dq*32 + 8*(m>>2) + 4*di + (m&3)      (bijective on [0,32))
    // => stage1 C at lane(q,l16), reg r covers d = dq*32 + 8q + 4di + r,
    //    exactly stage2's B-frag kdim ordering (kdim = quad*8 + j, j=4di+r).
    bf16x8 mA[2][2];
    {
        const float* mg = mhc + (size_t)n * MHCL * DD;
        #pragma unroll
        for (int di = 0; di < 2; ++di) {
            const int d = dq * 32 + 8 * (l16 >> 2) + 4 * di + (l16 & 3);
            u16 h0[8];
            #pragma unroll
            for (int j = 0; j < 8; ++j)
                h0[j] = f2bf(mg[(size_t)(quad * 8 + j) * DD + d]);
            __builtin_memcpy(&mA[di][0], h0, 16);
            u16 h1[8] = {0,0,0,0,0,0,0,0};
            if (quad == 0) {
                h1[0] = f2bf(mg[(size_t)32 * DD + d]);
                h1[1] = f2bf(mg[(size_t)33 * DD + d]);
            }
            __builtin_memcpy(&mA[di][1], h1, 16);
        }
    }

    // ---- pept staging: pure 16B bf16 copy from ws ----
    {
        const u16* pg = pb + (size_t)n * LL * DD;
        #pragma unroll 1
        for (int i = tid; i < (LL * DD) / 8; i += 256) {   // 640 16B chunks
            int row = i >> 4, c8 = (i & 15) << 3;
            u32x4 v;
            __builtin_memcpy(&v, __builtin_assume_aligned(pg + (size_t)row * DD + c8, 16), 16);
            __builtin_memcpy(__builtin_assume_aligned(&s_pept[row * PSTR + c8], 16), &v, 16);
        }
    }
    __syncthreads();

    // acc: out[t][o' = l16], partial over this wave's 32 d.
    // acc00: t = quad*4 + r; acc10: t = 16 + quad*4 + r.
    f32x4 acc00 = {0.f,0.f,0.f,0.f}, acc10 = acc00;

    // barrier-free drift k-loop; kern entirely in registers.
    #pragma unroll 3
    for (int k = 0; k < KK; ++k) {
        // stage1: kern[o'=16][d=32] for this k -> packed bf16 regs
        u32x2 kc[2];
        #pragma unroll
        for (int di = 0; di < 2; ++di) {
            f32x4 c0 = {0.f,0.f,0.f,0.f};
            c0 = mfma16(mA[di][0], wB[0], c0);
            c0 = mfma16(mA[di][1], wB[1], c0);
            kc[di][0] = pk2(fmaxf(c0[0], 0.f), fmaxf(c0[1], 0.f));
            kc[di][1] = pk2(fmaxf(c0[2], 0.f), fmaxf(c0[3], 0.f));
        }
        if (k < KK - 1) loadW(k + 1, wB);   // refill; latency covered by stage2
        // stage2: B-frag = stage1 registers (same lane), kdim = 32
        u32x4 b0 = { kc[0][0], kc[0][1], kc[1][0], kc[1][1] };
        bf16x8 bk0 = __builtin_bit_cast(bf16x8, b0);
        bf16x8 ap0 = ld8(&s_pept[(k + l16) * PSTR + dq * 32 + quad * 8]);
        bf16x8 ap1 = ld8(&s_pept[(k + 16 + l16) * PSTR + dq * 32 + quad * 8]);
        acc00 = mfma16(ap0, bk0, acc00);
        acc10 = mfma16(ap1, bk0, acc10);
    }

    // ---- 4-way d reduction: waves 1..3 park, wave 0 sums + bias + stores ----
    if (dq != 0) {
        float* ox = (float*)(s_mem + PEPT_U16 + (dq - 1) * EX_U16);
        const int fb = lane * 8;
        __builtin_memcpy(__builtin_assume_aligned(&ox[fb + 0], 16), &acc00, 16);
        __builtin_memcpy(__builtin_assume_aligned(&ox[fb + 4], 16), &acc10, 16);
    }
    __syncthreads();
    if (dq == 0) {
        const int fb = lane * 8;
        #pragma unroll
        for (int w = 0; w < 3; ++w) {
            const float* px = (const float*)(s_mem + PEPT_U16 + w * EX_U16);
            f32x4 q0, q1;
            __builtin_memcpy(&q0, __builtin_assume_aligned(&px[fb + 0], 16), 16);
            __builtin_memcpy(&q1, __builtin_assume_aligned(&px[fb + 4], 16), 16);
            acc00 += q0;
            acc10 += q1;
        }
        const float bv = bias[obase + l16];
        f32x4 r00 = acc00 + bv;
        f32x4 r10 = acc10 + bv;
        float* ob = out + ((size_t)n * OO + obase) * TT;
        __builtin_memcpy(__builtin_assume_aligned(ob + (size_t)l16 * TT + quad * 4, 16), &r00, 16);
        __builtin_memcpy(__builtin_assume_aligned(ob + (size_t)l16 * TT + 16 + quad * 4, 16), &r10, 16);
    }
}

// ---------- fallback (ws too small): R12's fp32 path, LDS kern (proven) ----------
__global__ __launch_bounds__(256, 2)
void iconv_ref(const float* __restrict__ pept,
               const float* __restrict__ mhc,
               const float* __restrict__ wgt,
               const float* __restrict__ bias,
               float* __restrict__ out)
{
    __shared__ __align__(16) u16 s_mem[PEPT_U16 + 4 * KS_U16];
    const int tid  = threadIdx.x;
    const int wave = tid >> 6;
    const int dh   = wave & 1;
    const int lane = tid & 63;
    const int quad = lane >> 4;
    const int l16  = lane & 15;
    const int n  = blockIdx.x >> 2;
    const int oq = blockIdx.x & 3;
    const int obase = (oq * 2 + (wave >> 1)) * 32;
    u16* const s_pept = s_mem;
    u16* const ks     = s_mem + PEPT_U16 + wave * KS_U16;

    auto loadW = [&](int o_base, int k, bf16x8 wF[2][2]) {
        #pragma unroll
        for (int mt = 0; mt < 2; ++mt) {
            const float* wrow = wgt + ((size_t)(o_base + mt * 16 + l16) * KK + k) * MHCL;
            float w8[8];
            __builtin_memcpy(w8, __builtin_assume_aligned(wrow + quad * 8, 8), 32);
            u16 h0[8];
            #pragma unroll
            for (int j = 0; j < 8; ++j) h0[j] = f2bf(w8[j]);
            __builtin_memcpy(&wF[mt][0], h0, 16);
            u16 h1[8] = {0,0,0,0,0,0,0,0};
            if (quad == 0) { h1[0] = f2bf(wrow[32]); h1[1] = f2bf(wrow[33]); }
            __builtin_memcpy(&wF[mt][1], h1, 16);
        }
    };

    bf16x8 wB[2][2];
    loadW(obase, 0, wB);

    bf16x8 mA[4][2];
    {
        const float* mg = mhc + (size_t)n * MHCL * DD;
        #pragma unroll
        for (int di = 0; di < 4; ++di) {
            const int d = dh * 64 + di * 16 + l16;
            u16 h0[8];
            #pragma unroll
            for (int j = 0; j < 8; ++j)
                h0[j] = f2bf(mg[(size_t)(quad * 8 + j) * DD + d]);
            __builtin_memcpy(&mA[di][0], h0, 16);
            u16 h1[8] = {0,0,0,0,0,0,0,0};
            if (quad == 0) {
                h1[0] = f2bf(mg[(size_t)32 * DD + d]);
                h1[1] = f2bf(mg[(size_t)33 * DD + d]);
            }
            __builtin_memcpy(&mA[di][1], h1, 16);
        }
    }

    {
        const float* pg = pept + (size_t)n * LL * DD;
        #pragma unroll 1
        for (int i = tid; i < (LL * DD) / 4; i += 256) {
            int row = i >> 5, c4 = (i & 31) << 2;
            f32x4 v;
            __builtin_memcpy(&v, __builtin_assume_aligned(pg + row * DD + c4, 16), 16);
            u32x2 h = { pk2(v[0], v[1]), pk2(v[2], v[3]) };
            __builtin_memcpy(__builtin_assume_aligned(&s_pept[row * PSTR + c4], 8), &h, 8);
        }
    }
    __syncthreads();

    f32x4 acc00 = {0.f,0.f,0.f,0.f}, acc01 = acc00, acc10 = acc00, acc11 = acc00;

    #pragma unroll 3
    for (int k = 0; k < KK; ++k) {
        #pragma unroll
        for (int di = 0; di < 4; ++di) {
            f32x4 c0 = {0.f,0.f,0.f,0.f}, c1 = c0;
            c0 = mfma16(mA[di][0], wB[0][0], c0);
            c0 = mfma16(mA[di][1], wB[0][1], c0);
            c1 = mfma16(mA[di][0], wB[1][0], c1);
            c1 = mfma16(mA[di][1], wB[1][1], c1);
            u32x2 p0 = { pk2(fmaxf(c0[0], 0.f), fmaxf(c0[1], 0.f)),
                         pk2(fmaxf(c0[2], 0.f), fmaxf(c0[3], 0.f)) };
            u32x2 p1 = { pk2(fmaxf(c1[0], 0.f), fmaxf(c1[1], 0.f)),
                         pk2(fmaxf(c1[2], 0.f), fmaxf(c1[3], 0.f)) };
            __builtin_memcpy(__builtin_assume_aligned(&ks[l16 * KDSTR + di * 16 + quad * 4], 8), &p0, 8);
            __builtin_memcpy(__builtin_assume_aligned(&ks[(16 + l16) * KDSTR + di * 16 + quad * 4], 8), &p1, 8);
        }
        if (k < KK - 1) loadW(obase, k + 1, wB);
        #pragma unroll
        for (int ds = 0; ds < 2; ++ds) {
            bf16x8 kb0 = ld8(&ks[l16 * KDSTR + ds * 32 + quad * 8]);
            bf16x8 kb1 = ld8(&ks[(16 + l16) * KDSTR + ds * 32 + quad * 8]);
            bf16x8 ap0 = ld8(&s_pept[(k + l16) * PSTR + dh * 64 + ds * 32 + quad * 8]);
            bf16x8 ap1 = ld8(&s_pept[(k + 16 + l16) * PSTR + dh * 64 + ds * 32 + quad * 8]);
            acc00 = mfma16(ap0, kb0, acc00);
            acc01 = mfma16(ap0, kb1, acc01);
            acc10 = mfma16(ap1, kb0, acc10);
            acc11 = mfma16(ap1, kb1, acc11);
        }
    }

    if (dh == 1) {
        float* ox = (float*)ks;
        const int fb = lane * 16;
        __builtin_memcpy(__builtin_assume_aligned(&ox[fb +  0], 16), &acc00, 16);
        __builtin_memcpy(__builtin_assume_aligned(&ox[fb +  4], 16), &acc01, 16);
        __builtin_memcpy(__builtin_assume_aligned(&ox[fb +  8], 16), &acc10, 16);
        __builtin_memcpy(__builtin_assume_aligned(&ox[fb + 12], 16), &acc11, 16);
    }
    __syncthreads();
    if (dh == 0) {
        const float* px = (const float*)(s_mem + PEPT_U16 + (wave + 1) * KS_U16);
        const int fb = lane * 16;
        f32x4 q00, q01, q10, q11;
        __builtin_memcpy(&q00, __builtin_assume_aligned(&px[fb +  0], 16), 16);
        __builtin_memcpy(&q01, __builtin_assume_aligned(&px[fb +  4], 16), 16);
        __builtin_memcpy(&q10, __builtin_assume_aligned(&px[fb +  8], 16), 16);
        __builtin_memcpy(&q11, __builtin_assume_aligned(&px[fb + 12], 16), 16);
        const float bv0 = bias[obase + l16];
        const float bv1 = bias[obase + 16 + l16];
        f32x4 r00 = acc00 + q00 + bv0;
        f32x4 r01 = acc01 + q01 + bv1;
        f32x4 r10 = acc10 + q10 + bv0;
        f32x4 r11 = acc11 + q11 + bv1;
        float* ob = out + ((size_t)n * OO + obase) * TT;
        __builtin_memcpy(__builtin_assume_aligned(ob + (size_t)l16 * TT + quad * 4, 16), &r00, 16);
        __builtin_memcpy(__builtin_assume_aligned(ob + (size_t)(16 + l16) * TT + quad * 4, 16), &r01, 16);
        __builtin_memcpy(__builtin_assume_aligned(ob + (size_t)l16 * TT + 16 + quad * 4, 16), &r10, 16);
        __builtin_memcpy(__builtin_assume_aligned(ob + (size_t)(16 + l16) * TT + 16 + quad * 4, 16), &r11, 16);
    }
}

extern "C" void kernel_launch(void* const* d_in, const int* in_sizes, int n_in,
                              void* d_out, int out_size, void* d_ws, size_t ws_size,
                              hipStream_t stream) {
    const float* pept = (const float*)d_in[0];
    const float* mhc  = (const float*)d_in[1];
    const float* wgt  = (const float*)d_in[2];
    const float* bias = (const float*)d_in[3];
    float* out = (float*)d_out;

    const size_t w_bytes = (size_t)OO * KK * WPADL * sizeof(u16);   // 294,912
    const size_t p_bytes = (size_t)NN * LL * DD * sizeof(u16);      // 5,242,880
    if (ws_size >= w_bytes + p_bytes) {
        u16* wp = (u16*)d_ws;
        u16* pp = (u16*)((char*)d_ws + w_bytes);
        const int total = OO * KK * (WPADL / 2) + NN * LL * DD / 2;  // 1,347,584
        cvt_all<<<dim3((total + 255) / 256), dim3(256), 0, stream>>>(wgt, pept, (u32*)wp, (u32*)pp);
        iconv_fast<<<dim3(NN * 16), dim3(256), 0, stream>>>(mhc, wp, pp, bias, out);
    } else {
        iconv_ref<<<dim3(NN * 4), dim3(256), 0, stream>>>(pept, mhc, wgt, bias, out);
    }
}

// Round 15
// 118.212 us; speedup vs baseline: 1.2421x; 1.2421x over previous
//
#include <hip/hip_runtime.h>
#include <hip/hip_bf16.h>

typedef unsigned short u16;
typedef unsigned int u32;
typedef __bf16 bf16x8 __attribute__((ext_vector_type(8)));
typedef float f32x4 __attribute__((ext_vector_type(4)));
typedef unsigned int u32x4 __attribute__((ext_vector_type(4)));
typedef unsigned int u32x2 __attribute__((ext_vector_type(2)));

#define NN 512
#define LL 40
#define DD 128
#define OO 256
#define KK 9
#define MHCL 34
#define TT 32
#define PSTR 136   // pept LDS row stride (u16)
#define KDSTR 72   // fallback kernel only
#define WPADL 64   // padded l-dim in preconverted W

#define PEPT_U16 (LL * PSTR)    // 5440 u16 = 10880 B
#define KS_U16   (32 * KDSTR)   // fallback only
#define EX_U16   2048           // pair exchange buffer: 64 lanes x 16 f32 = 4096 B

__device__ __forceinline__ u16 f2bf(float x) {
    unsigned int u = __builtin_bit_cast(unsigned int, x);
    u = (u + 0x7FFFu + ((u >> 16) & 1u)) >> 16;
    return (u16)u;
}
__device__ __forceinline__ u32 pk2(float a, float b) {
    __hip_bfloat162 h = __float22bfloat162_rn(make_float2(a, b)); // x = low half
    u32 r;
    __builtin_memcpy(&r, &h, 4);
    return r;
}
__device__ __forceinline__ bf16x8 ld8(const u16* p) {   // LDS or global, 16B
    u32x4 r;
    __builtin_memcpy(&r, __builtin_assume_aligned(p, 16), 16);
    return __builtin_bit_cast(bf16x8, r);
}
__device__ __forceinline__ f32x4 mfma16(bf16x8 a, bf16x8 b, f32x4 c) {
    return __builtin_amdgcn_mfma_f32_16x16x32_bf16(a, b, c, 0, 0, 0);
}

// fused prologue: W fp32 [O][K][34] -> bf16 [O][K][64] padded, AND
// pept fp32 [N][L][D] -> bf16 same layout. One dispatch.
__global__ void cvt_all(const float* __restrict__ wgt, const float* __restrict__ pept,
                        u32* __restrict__ wp, u32* __restrict__ pp) {
    int i = blockIdx.x * 256 + threadIdx.x;
    const int WN = OO * KK * (WPADL / 2);            // 36864
    if (i < WN) {
        int o = i / (KK * (WPADL / 2));
        int r = i - o * (KK * (WPADL / 2));
        int k = r >> 5;
        int lp = (r & 31) << 1;
        const float* src = wgt + ((size_t)o * KK + k) * MHCL;
        float a = (lp     < MHCL) ? src[lp]     : 0.f;
        float b = (lp + 1 < MHCL) ? src[lp + 1] : 0.f;
        wp[i] = pk2(a, b);
    } else {
        size_t j = (size_t)(i - WN);
        if (j < (size_t)NN * LL * DD / 2)
            pp[j] = pk2(pept[2 * j], pept[2 * j + 1]);
    }
}

// R15 = R13 (best verified, 48.5us: in-register kern via mA permutation,
// zero-barrier drift k-loop) + W DOUBLE-BUFFER & FULL K-UNROLL.
// R14 closed the occupancy axis: quarter-tile raised occupancy 34->75% and
// LOST 33us (per-wave ILP collapse + 4x prologues). Binding constraint is
// the per-wave critical path. Remaining weakness in R13: loadW(k+1) issues
// AFTER stage1(k) frees wB, so its ~200-500cy latency is covered only by
// stage2's ~60cy. Here wBuf[2][..] alternates, loadW(k+1) issues at the TOP
// of step k (full-step cover), and the 9-step loop is fully unrolled so the
// scheduler can slide stage1(k+1) into stage2(k)'s shadow (all-register,
// no barriers -> legal). +16 VGPR (~106 unified, under the 128 step).
// Tripwire: WRITE >25MB = spill -> revert to single wB.
__global__ __launch_bounds__(256, 2)
void iconv_fast(const float* __restrict__ mhc,
                const u16* __restrict__ wp,
                const u16* __restrict__ pb,
                const float* __restrict__ bias,
                float* __restrict__ out)
{
    // LDS 19072 B: pept[40][136] | 2 x pair-exchange f32[64][16]
    __shared__ __align__(16) u16 s_mem[PEPT_U16 + 2 * EX_U16];

    const int tid  = threadIdx.x;
    const int wave = tid >> 6;
    const int pair = wave >> 1;     // pair index within block (0,1)
    const int dh   = wave & 1;      // d-half owner: d in [dh*64, dh*64+64)
    const int lane = tid & 63;
    const int quad = lane >> 4;
    const int l16  = lane & 15;

    const int n  = blockIdx.x >> 2;     // 4 blocks per sample
    const int oq = blockIdx.x & 3;      // o-quarter: chunks {oq*2, oq*2+1}
    const int obase = (oq * 2 + pair) * 32;   // this pair's single o-chunk

    u16* const s_pept = s_mem;

    auto loadW = [&](int o_base, int k, bf16x8 wF[2][2]) {
        #pragma unroll
        for (int mt = 0; mt < 2; ++mt) {
            const u16* wr = wp + ((size_t)(o_base + mt * 16 + l16) * KK + k) * WPADL;
            u32x4 r0, r1;
            __builtin_memcpy(&r0, __builtin_assume_aligned(wr + quad * 8, 16), 16);
            __builtin_memcpy(&r1, __builtin_assume_aligned(wr + 32 + quad * 8, 16), 16);
            wF[mt][0] = __builtin_bit_cast(bf16x8, r0);
            wF[mt][1] = __builtin_bit_cast(bf16x8, r1);
        }
    };

    // W double-buffer; k=0 fragments in flight under the prologue
    bf16x8 wBuf[2][2][2];
    loadW(obase, 0, wBuf[0]);

    // ---- mA DIRECT from global fp32, with PERMUTED d-rows ----
    // A-frag row m (= l16) of sub-matrix di maps to
    //   d = dh*64 + 32*(di&1) + 8*(m>>2) + 4*(di>>1) + (m&3)
    // (bijective on [0,64)). Consequence: stage1 C at lane(q,l16), reg r
    // covers d = 32(di&1)+8q+4(di>>1)+r — exactly stage2's B-frag ordering.
    bf16x8 mA[4][2];
    {
        const float* mg = mhc + (size_t)n * MHCL * DD;
        #pragma unroll
        for (int di = 0; di < 4; ++di) {
            const int d = dh * 64 + 32 * (di & 1) + 8 * (l16 >> 2) + 4 * (di >> 1) + (l16 & 3);
            u16 h0[8];
            #pragma unroll
            for (int j = 0; j < 8; ++j)
                h0[j] = f2bf(mg[(size_t)(quad * 8 + j) * DD + d]);
            __builtin_memcpy(&mA[di][0], h0, 16);
            u16 h1[8] = {0,0,0,0,0,0,0,0};
            if (quad == 0) {
                h1[0] = f2bf(mg[(size_t)32 * DD + d]);
                h1[1] = f2bf(mg[(size_t)33 * DD + d]);
            }
            __builtin_memcpy(&mA[di][1], h1, 16);
        }
    }

    // ---- pept staging: pure 16B bf16 copy from ws ----
    {
        const u16* pg = pb + (size_t)n * LL * DD;
        #pragma unroll 1
        for (int i = tid; i < (LL * DD) / 8; i += 256) {   // 640 16B chunks
            int row = i >> 4, c8 = (i & 15) << 3;
            u32x4 v;
            __builtin_memcpy(&v, __builtin_assume_aligned(pg + (size_t)row * DD + c8, 16), 16);
            __builtin_memcpy(__builtin_assume_aligned(&s_pept[row * PSTR + c8], 16), &v, 16);
        }
    }
    __syncthreads();

    // acc[ti][oj]: out[t = ti*16 + quad*4 + r][o' = oj*16 + l16], partial over this d-half
    f32x4 acc00 = {0.f,0.f,0.f,0.f}, acc01 = acc00, acc10 = acc00, acc11 = acc00;

    // FULLY-UNROLLED zero-barrier k-loop: W(k+1) load issues at the top of
    // step k (entire step covers its latency); stage1/stage2 all-register.
    #pragma unroll
    for (int k = 0; k < KK; ++k) {
        if (k < KK - 1) loadW(obase, k + 1, wBuf[(k + 1) & 1]);  // full-step cover
        const bf16x8 (*wB)[2] = wBuf[k & 1];

        // stage1: kern for this k, packed bf16 pairs in registers
        u32x2 kc0[4], kc1[4];
        #pragma unroll
        for (int di = 0; di < 4; ++di) {
            f32x4 c0 = {0.f,0.f,0.f,0.f}, c1 = c0;
            c0 = mfma16(mA[di][0], wB[0][0], c0);   // C[d(di,m)][o' 0..15]
            c0 = mfma16(mA[di][1], wB[0][1], c0);
            c1 = mfma16(mA[di][0], wB[1][0], c1);   // C[d(di,m)][o' 16..31]
            c1 = mfma16(mA[di][1], wB[1][1], c1);
            kc0[di][0] = pk2(fmaxf(c0[0], 0.f), fmaxf(c0[1], 0.f));
            kc0[di][1] = pk2(fmaxf(c0[2], 0.f), fmaxf(c0[3], 0.f));
            kc1[di][0] = pk2(fmaxf(c1[0], 0.f), fmaxf(c1[1], 0.f));
            kc1[di][1] = pk2(fmaxf(c1[2], 0.f), fmaxf(c1[3], 0.f));
        }
        // stage2: B-frags assembled from stage1 registers (same lane)
        #pragma unroll
        for (int ds = 0; ds < 2; ++ds) {
            u32x4 b0 = { kc0[ds][0], kc0[ds][1], kc0[ds + 2][0], kc0[ds + 2][1] };
            u32x4 b1 = { kc1[ds][0], kc1[ds][1], kc1[ds + 2][0], kc1[ds + 2][1] };
            bf16x8 bk0 = __builtin_bit_cast(bf16x8, b0);
            bf16x8 bk1 = __builtin_bit_cast(bf16x8, b1);
            bf16x8 ap0 = ld8(&s_pept[(k + l16) * PSTR + dh * 64 + ds * 32 + quad * 8]);
            bf16x8 ap1 = ld8(&s_pept[(k + 16 + l16) * PSTR + dh * 64 + ds * 32 + quad * 8]);
            acc00 = mfma16(ap0, bk0, acc00);
            acc01 = mfma16(ap0, bk1, acc01);
            acc10 = mfma16(ap1, bk0, acc10);
            acc11 = mfma16(ap1, bk1, acc11);
        }
    }

    // ---- pair reduction: odd wave parks acc in pair buffer; even sums+stores ----
    if (dh == 1) {
        float* ox = (float*)(s_mem + PEPT_U16 + pair * EX_U16);
        const int fb = lane * 16;
        __builtin_memcpy(__builtin_assume_aligned(&ox[fb +  0], 16), &acc00, 16);
        __builtin_memcpy(__builtin_assume_aligned(&ox[fb +  4], 16), &acc01, 16);
        __builtin_memcpy(__builtin_assume_aligned(&ox[fb +  8], 16), &acc10, 16);
        __builtin_memcpy(__builtin_assume_aligned(&ox[fb + 12], 16), &acc11, 16);
    }
    __syncthreads();
    if (dh == 0) {
        const float* px = (const float*)(s_mem + PEPT_U16 + pair * EX_U16);
        const int fb = lane * 16;
        f32x4 q00, q01, q10, q11;
        __builtin_memcpy(&q00, __builtin_assume_aligned(&px[fb +  0], 16), 16);
        __builtin_memcpy(&q01, __builtin_assume_aligned(&px[fb +  4], 16), 16);
        __builtin_memcpy(&q10, __builtin_assume_aligned(&px[fb +  8], 16), 16);
        __builtin_memcpy(&q11, __builtin_assume_aligned(&px[fb + 12], 16), 16);
        const float bv0 = bias[obase + l16];
        const float bv1 = bias[obase + 16 + l16];
        f32x4 r00 = acc00 + q00 + bv0;
        f32x4 r01 = acc01 + q01 + bv1;
        f32x4 r10 = acc10 + q10 + bv0;
        f32x4 r11 = acc11 + q11 + bv1;
        float* ob = out + ((size_t)n * OO + obase) * TT;
        __builtin_memcpy(__builtin_assume_aligned(ob + (size_t)l16 * TT + quad * 4, 16), &r00, 16);
        __builtin_memcpy(__builtin_assume_aligned(ob + (size_t)(16 + l16) * TT + quad * 4, 16), &r01, 16);
        __builtin_memcpy(__builtin_assume_aligned(ob + (size_t)l16 * TT + 16 + quad * 4, 16), &r10, 16);
        __builtin_memcpy(__builtin_assume_aligned(ob + (size_t)(16 + l16) * TT + 16 + quad * 4, 16), &r11, 16);
    }
}

// ---------- fallback (ws too small): R12's fp32 path, LDS kern (proven) ----------
__global__ __launch_bounds__(256, 2)
void iconv_ref(const float* __restrict__ pept,
               const float* __restrict__ mhc,
               const float* __restrict__ wgt,
               const float* __restrict__ bias,
               float* __restrict__ out)
{
    __shared__ __align__(16) u16 s_mem[PEPT_U16 + 4 * KS_U16];
    const int tid  = threadIdx.x;
    const int wave = tid >> 6;
    const int dh   = wave & 1;
    const int lane = tid & 63;
    const int quad = lane >> 4;
    const int l16  = lane & 15;
    const int n  = blockIdx.x >> 2;
    const int oq = blockIdx.x & 3;
    const int obase = (oq * 2 + (wave >> 1)) * 32;
    u16* const s_pept = s_mem;
    u16* const ks     = s_mem + PEPT_U16 + wave * KS_U16;

    auto loadW = [&](int o_base, int k, bf16x8 wF[2][2]) {
        #pragma unroll
        for (int mt = 0; mt < 2; ++mt) {
            const float* wrow = wgt + ((size_t)(o_base + mt * 16 + l16) * KK + k) * MHCL;
            float w8[8];
            __builtin_memcpy(w8, __builtin_assume_aligned(wrow + quad * 8, 8), 32);
            u16 h0[8];
            #pragma unroll
            for (int j = 0; j < 8; ++j) h0[j] = f2bf(w8[j]);
            __builtin_memcpy(&wF[mt][0], h0, 16);
            u16 h1[8] = {0,0,0,0,0,0,0,0};
            if (quad == 0) { h1[0] = f2bf(wrow[32]); h1[1] = f2bf(wrow[33]); }
            __builtin_memcpy(&wF[mt][1], h1, 16);
        }
    };

    bf16x8 wB[2][2];
    loadW(obase, 0, wB);

    bf16x8 mA[4][2];
    {
        const float* mg = mhc + (size_t)n * MHCL * DD;
        #pragma unroll
        for (int di = 0; di < 4; ++di) {
            const int d = dh * 64 + di * 16 + l16;
            u16 h0[8];
            #pragma unroll
            for (int j = 0; j < 8; ++j)
                h0[j] = f2bf(mg[(size_t)(quad * 8 + j) * DD + d]);
            __builtin_memcpy(&mA[di][0], h0, 16);
            u16 h1[8] = {0,0,0,0,0,0,0,0};
            if (quad == 0) {
                h1[0] = f2bf(mg[(size_t)32 * DD + d]);
                h1[1] = f2bf(mg[(size_t)33 * DD + d]);
            }
            __builtin_memcpy(&mA[di][1], h1, 16);
        }
    }

    {
        const float* pg = pept + (size_t)n * LL * DD;
        #pragma unroll 1
        for (int i = tid; i < (LL * DD) / 4; i += 256) {
            int row = i >> 5, c4 = (i & 31) << 2;
            f32x4 v;
            __builtin_memcpy(&v, __builtin_assume_aligned(pg + row * DD + c4, 16), 16);
            u32x2 h = { pk2(v[0], v[1]), pk2(v[2], v[3]) };
            __builtin_memcpy(__builtin_assume_aligned(&s_pept[row * PSTR + c4], 8), &h, 8);
        }
    }
    __syncthreads();

    f32x4 acc00 = {0.f,0.f,0.f,0.f}, acc01 = acc00, acc10 = acc00, acc11 = acc00;

    #pragma unroll 3
    for (int k = 0; k < KK; ++k) {
        #pragma unroll
        for (int di = 0; di < 4; ++di) {
            f32x4 c0 = {0.f,0.f,0.f,0.f}, c1 = c0;
            c0 = mfma16(mA[di][0], wB[0][0], c0);
            c0 = mfma16(mA[di][1], wB[0][1], c0);
            c1 = mfma16(mA[di][0], wB[1][0], c1);
            c1 = mfma16(mA[di][1], wB[1][1], c1);
            u32x2 p0 = { pk2(fmaxf(c0[0], 0.f), fmaxf(c0[1], 0.f)),
                         pk2(fmaxf(c0[2], 0.f), fmaxf(c0[3], 0.f)) };
            u32x2 p1 = { pk2(fmaxf(c1[0], 0.f), fmaxf(c1[1], 0.f)),
                         pk2(fmaxf(c1[2], 0.f), fmaxf(c1[3], 0.f)) };
            __builtin_memcpy(__builtin_assume_aligned(&ks[l16 * KDSTR + di * 16 + quad * 4], 8), &p0, 8);
            __builtin_memcpy(__builtin_assume_aligned(&ks[(16 + l16) * KDSTR + di * 16 + quad * 4], 8), &p1, 8);
        }
        if (k < KK - 1) loadW(obase, k + 1, wB);
        #pragma unroll
        for (int ds = 0; ds < 2; ++ds) {
            bf16x8 kb0 = ld8(&ks[l16 * KDSTR + ds * 32 + quad * 8]);
            bf16x8 kb1 = ld8(&ks[(16 + l16) * KDSTR + ds * 32 + quad * 8]);
            bf16x8 ap0 = ld8(&s_pept[(k + l16) * PSTR + dh * 64 + ds * 32 + quad * 8]);
            bf16x8 ap1 = ld8(&s_pept[(k + 16 + l16) * PSTR + dh * 64 + ds * 32 + quad * 8]);
            acc00 = mfma16(ap0, kb0, acc00);
            acc01 = mfma16(ap0, kb1, acc01);
            acc10 = mfma16(ap1, kb0, acc10);
            acc11 = mfma16(ap1, kb1, acc11);
        }
    }

    if (dh == 1) {
        float* ox = (float*)ks;
        const int fb = lane * 16;
        __builtin_memcpy(__builtin_assume_aligned(&ox[fb +  0], 16), &acc00, 16);
        __builtin_memcpy(__builtin_assume_aligned(&ox[fb +  4], 16), &acc01, 16);
        __builtin_memcpy(__builtin_assume_aligned(&ox[fb +  8], 16), &acc10, 16);
        __builtin_memcpy(__builtin_assume_aligned(&ox[fb + 12], 16), &acc11, 16);
    }
    __syncthreads();
    if (dh == 0) {
        const float* px = (const float*)(s_mem + PEPT_U16 + (wave + 1) * KS_U16);
        const int fb = lane * 16;
        f32x4 q00, q01, q10, q11;
        __builtin_memcpy(&q00, __builtin_assume_aligned(&px[fb +  0], 16), 16);
        __builtin_memcpy(&q01, __builtin_assume_aligned(&px[fb +  4], 16), 16);
        __builtin_memcpy(&q10, __builtin_assume_aligned(&px[fb +  8], 16), 16);
        __builtin_memcpy(&q11, __builtin_assume_aligned(&px[fb + 12], 16), 16);
        const float bv0 = bias[obase + l16];
        const float bv1 = bias[obase + 16 + l16];
        f32x4 r00 = acc00 + q00 + bv0;
        f32x4 r01 = acc01 + q01 + bv1;
        f32x4 r10 = acc10 + q10 + bv0;
        f32x4 r11 = acc11 + q11 + bv1;
        float* ob = out + ((size_t)n * OO + obase) * TT;
        __builtin_memcpy(__builtin_assume_aligned(ob + (size_t)l16 * TT + quad * 4, 16), &r00, 16);
        __builtin_memcpy(__builtin_assume_aligned(ob + (size_t)(16 + l16) * TT + quad * 4, 16), &r01, 16);
        __builtin_memcpy(__builtin_assume_aligned(ob + (size_t)l16 * TT + 16 + quad * 4, 16), &r10, 16);
        __builtin_memcpy(__builtin_assume_aligned(ob + (size_t)(16 + l16) * TT + 16 + quad * 4, 16), &r11, 16);
    }
}

extern "C" void kernel_launch(void* const* d_in, const int* in_sizes, int n_in,
                              void* d_out, int out_size, void* d_ws, size_t ws_size,
                              hipStream_t stream) {
    const float* pept = (const float*)d_in[0];
    const float* mhc  = (const float*)d_in[1];
    const float* wgt  = (const float*)d_in[2];
    const float* bias = (const float*)d_in[3];
    float* out = (float*)d_out;

    const size_t w_bytes = (size_t)OO * KK * WPADL * sizeof(u16);   // 294,912
    const size_t p_bytes = (size_t)NN * LL * DD * sizeof(u16);      // 5,242,880
    if (ws_size >= w_bytes + p_bytes) {
        u16* wp = (u16*)d_ws;
        u16* pp = (u16*)((char*)d_ws + w_bytes);
        const int total = OO * KK * (WPADL / 2) + NN * LL * DD / 2;  // 1,347,584
        cvt_all<<<dim3((total + 255) / 256), dim3(256), 0, stream>>>(wgt, pept, (u32*)wp, (u32*)pp);
        iconv_fast<<<dim3(NN * 4), dim3(256), 0, stream>>>(mhc, wp, pp, bias, out);
    } else {
        iconv_ref<<<dim3(NN * 4), dim3(256), 0, stream>>>(pept, mhc, wgt, bias, out);
    }
}

// Round 16
// 116.443 us; speedup vs baseline: 1.2609x; 1.0152x over previous
//
#include <hip/hip_runtime.h>
#include <hip/hip_bf16.h>

typedef unsigned short u16;
typedef unsigned int u32;
typedef __bf16 bf16x8 __attribute__((ext_vector_type(8)));
typedef float f32x4 __attribute__((ext_vector_type(4)));
typedef unsigned int u32x4 __attribute__((ext_vector_type(4)));
typedef unsigned int u32x2 __attribute__((ext_vector_type(2)));

#define NN 512
#define LL 40
#define DD 128
#define OO 256
#define KK 9
#define MHCL 34
#define TT 32
#define PSTR 136   // pept LDS row stride (u16)
#define KDSTR 72   // kern_s row stride (fallback kernel only)
#define WPADL 64   // padded l-dim in preconverted W

#define PEPT_U16 (LL * PSTR)    // 5440 u16 = 10880 B
#define KS_U16   (32 * KDSTR)   // fallback only
#define EX_U16   2048           // pair exchange buffer: 64 lanes x 16 f32 = 4096 B

__device__ __forceinline__ u16 f2bf(float x) {
    unsigned int u = __builtin_bit_cast(unsigned int, x);
    u = (u + 0x7FFFu + ((u >> 16) & 1u)) >> 16;
    return (u16)u;
}
__device__ __forceinline__ u32 pk2(float a, float b) {
    __hip_bfloat162 h = __float22bfloat162_rn(make_float2(a, b)); // x = low half
    u32 r;
    __builtin_memcpy(&r, &h, 4);
    return r;
}
__device__ __forceinline__ bf16x8 ld8(const u16* p) {   // LDS or global, 16B
    u32x4 r;
    __builtin_memcpy(&r, __builtin_assume_aligned(p, 16), 16);
    return __builtin_bit_cast(bf16x8, r);
}
__device__ __forceinline__ f32x4 mfma16(bf16x8 a, bf16x8 b, f32x4 c) {
    return __builtin_amdgcn_mfma_f32_16x16x32_bf16(a, b, c, 0, 0, 0);
}

// fused prologue: W fp32 [O][K][34] -> bf16 [O][K][64] padded, AND
// pept fp32 [N][L][D] -> bf16 same layout. One dispatch.
__global__ void cvt_all(const float* __restrict__ wgt, const float* __restrict__ pept,
                        u32* __restrict__ wp, u32* __restrict__ pp) {
    int i = blockIdx.x * 256 + threadIdx.x;
    const int WN = OO * KK * (WPADL / 2);            // 36864
    if (i < WN) {
        int o = i / (KK * (WPADL / 2));
        int r = i - o * (KK * (WPADL / 2));
        int k = r >> 5;
        int lp = (r & 31) << 1;
        const float* src = wgt + ((size_t)o * KK + k) * MHCL;
        float a = (lp     < MHCL) ? src[lp]     : 0.f;
        float b = (lp + 1 < MHCL) ? src[lp + 1] : 0.f;
        wp[i] = pk2(a, b);
    } else {
        size_t j = (size_t)(i - WN);
        if (j < (size_t)NN * LL * DD / 2)
            pp[j] = pk2(pept[2 * j], pept[2 * j + 1]);
    }
}

// FINAL (R16 = R13, best verified: ~48.5us iconv, 117us bench).
// Session ledger: R7 lockstep-breaking wave-private drift (-30%), R12/R13
// conversion-hoisting + in-register kern (-9%). Falsified: TLP/occupancy
// (R2/R9/R14: raising occupancy 34->75% LOST 33us), LDS-RAW (R4/R13),
// ILP width (R6), global-operand inner-loop (R11, +25us), W-dbuf+unroll
// (R15, null). Floor arithmetic: fused kern is mandatory (materializing =
// 604MB traffic ~ 96us > 48.5); per-k-step dependent chain ~600cy x 18
// steps at 4 waves/SIMD (unified-VGPR step) ~= the measured 48.5us.
__global__ __launch_bounds__(256, 2)
void iconv_fast(const float* __restrict__ mhc,
                const u16* __restrict__ wp,
                const u16* __restrict__ pb,
                const float* __restrict__ bias,
                float* __restrict__ out)
{
    // LDS 19072 B: pept[40][136] | 2 x pair-exchange f32[64][16]
    __shared__ __align__(16) u16 s_mem[PEPT_U16 + 2 * EX_U16];

    const int tid  = threadIdx.x;
    const int wave = tid >> 6;
    const int pair = wave >> 1;     // pair index within block (0,1)
    const int dh   = wave & 1;      // d-half owner: d in [dh*64, dh*64+64)
    const int lane = tid & 63;
    const int quad = lane >> 4;
    const int l16  = lane & 15;

    const int n  = blockIdx.x >> 2;     // 4 blocks per sample
    const int oq = blockIdx.x & 3;      // o-quarter: chunks {oq*2, oq*2+1}
    const int obase = (oq * 2 + pair) * 32;   // this pair's single o-chunk

    u16* const s_pept = s_mem;

    auto loadW = [&](int o_base, int k, bf16x8 wF[2][2]) {
        #pragma unroll
        for (int mt = 0; mt < 2; ++mt) {
            const u16* wr = wp + ((size_t)(o_base + mt * 16 + l16) * KK + k) * WPADL;
            u32x4 r0, r1;
            __builtin_memcpy(&r0, __builtin_assume_aligned(wr + quad * 8, 16), 16);
            __builtin_memcpy(&r1, __builtin_assume_aligned(wr + 32 + quad * 8, 16), 16);
            wF[mt][0] = __builtin_bit_cast(bf16x8, r0);
            wF[mt][1] = __builtin_bit_cast(bf16x8, r1);
        }
    };

    // first W fragments in flight under the prologue
    bf16x8 wB[2][2];
    loadW(obase, 0, wB);

    // ---- mA DIRECT from global fp32, with PERMUTED d-rows ----
    // A-frag row m (= l16) of sub-matrix di maps to
    //   d = dh*64 + 32*(di&1) + 8*(m>>2) + 4*(di>>1) + (m&3)
    // (bijective on [0,64)). Consequence: stage1 C at lane(q,l16), reg r
    // covers d = 32(di&1)+8q+4(di>>1)+r — exactly stage2's B-frag ordering.
    bf16x8 mA[4][2];
    {
        const float* mg = mhc + (size_t)n * MHCL * DD;
        #pragma unroll
        for (int di = 0; di < 4; ++di) {
            const int d = dh * 64 + 32 * (di & 1) + 8 * (l16 >> 2) + 4 * (di >> 1) + (l16 & 3);
            u16 h0[8];
            #pragma unroll
            for (int j = 0; j < 8; ++j)
                h0[j] = f2bf(mg[(size_t)(quad * 8 + j) * DD + d]);
            __builtin_memcpy(&mA[di][0], h0, 16);
            u16 h1[8] = {0,0,0,0,0,0,0,0};
            if (quad == 0) {
                h1[0] = f2bf(mg[(size_t)32 * DD + d]);
                h1[1] = f2bf(mg[(size_t)33 * DD + d]);
            }
            __builtin_memcpy(&mA[di][1], h1, 16);
        }
    }

    // ---- pept staging: pure 16B bf16 copy from ws ----
    {
        const u16* pg = pb + (size_t)n * LL * DD;
        #pragma unroll 1
        for (int i = tid; i < (LL * DD) / 8; i += 256) {   // 640 16B chunks
            int row = i >> 4, c8 = (i & 15) << 3;
            u32x4 v;
            __builtin_memcpy(&v, __builtin_assume_aligned(pg + (size_t)row * DD + c8, 16), 16);
            __builtin_memcpy(__builtin_assume_aligned(&s_pept[row * PSTR + c8], 16), &v, 16);
        }
    }
    __syncthreads();

    // acc[ti][oj]: out[t = ti*16 + quad*4 + r][o' = oj*16 + l16], partial over this d-half
    f32x4 acc00 = {0.f,0.f,0.f,0.f}, acc01 = acc00, acc10 = acc00, acc11 = acc00;

    // k-loop: stage1 -> registers -> stage2, zero LDS on the kern path,
    // zero barriers, wave-drift preserved.
    #pragma unroll 3
    for (int k = 0; k < KK; ++k) {
        // stage1: kern for this k, packed bf16 pairs in registers
        u32x2 kc0[4], kc1[4];
        #pragma unroll
        for (int di = 0; di < 4; ++di) {
            f32x4 c0 = {0.f,0.f,0.f,0.f}, c1 = c0;
            c0 = mfma16(mA[di][0], wB[0][0], c0);   // C[d(di,m)][o' 0..15]
            c0 = mfma16(mA[di][1], wB[0][1], c0);
            c1 = mfma16(mA[di][0], wB[1][0], c1);   // C[d(di,m)][o' 16..31]
            c1 = mfma16(mA[di][1], wB[1][1], c1);
            kc0[di][0] = pk2(fmaxf(c0[0], 0.f), fmaxf(c0[1], 0.f));
            kc0[di][1] = pk2(fmaxf(c0[2], 0.f), fmaxf(c0[3], 0.f));
            kc1[di][0] = pk2(fmaxf(c1[0], 0.f), fmaxf(c1[1], 0.f));
            kc1[di][1] = pk2(fmaxf(c1[2], 0.f), fmaxf(c1[3], 0.f));
        }
        // refill wB (fully consumed); latency covered by stage2
        if (k < KK - 1) loadW(obase, k + 1, wB);
        // stage2: B-frags assembled from stage1 registers (same lane)
        #pragma unroll
        for (int ds = 0; ds < 2; ++ds) {
            u32x4 b0 = { kc0[ds][0], kc0[ds][1], kc0[ds + 2][0], kc0[ds + 2][1] };
            u32x4 b1 = { kc1[ds][0], kc1[ds][1], kc1[ds + 2][0], kc1[ds + 2][1] };
            bf16x8 bk0 = __builtin_bit_cast(bf16x8, b0);
            bf16x8 bk1 = __builtin_bit_cast(bf16x8, b1);
            bf16x8 ap0 = ld8(&s_pept[(k + l16) * PSTR + dh * 64 + ds * 32 + quad * 8]);
            bf16x8 ap1 = ld8(&s_pept[(k + 16 + l16) * PSTR + dh * 64 + ds * 32 + quad * 8]);
            acc00 = mfma16(ap0, bk0, acc00);
            acc01 = mfma16(ap0, bk1, acc01);
            acc10 = mfma16(ap1, bk0, acc10);
            acc11 = mfma16(ap1, bk1, acc11);
        }
    }

    // ---- pair reduction: odd wave parks acc in pair buffer; even sums+stores ----
    if (dh == 1) {
        float* ox = (float*)(s_mem + PEPT_U16 + pair * EX_U16);
        const int fb = lane * 16;
        __builtin_memcpy(__builtin_assume_aligned(&ox[fb +  0], 16), &acc00, 16);
        __builtin_memcpy(__builtin_assume_aligned(&ox[fb +  4], 16), &acc01, 16);
        __builtin_memcpy(__builtin_assume_aligned(&ox[fb +  8], 16), &acc10, 16);
        __builtin_memcpy(__builtin_assume_aligned(&ox[fb + 12], 16), &acc11, 16);
    }
    __syncthreads();
    if (dh == 0) {
        const float* px = (const float*)(s_mem + PEPT_U16 + pair * EX_U16);
        const int fb = lane * 16;
        f32x4 q00, q01, q10, q11;
        __builtin_memcpy(&q00, __builtin_assume_aligned(&px[fb +  0], 16), 16);
        __builtin_memcpy(&q01, __builtin_assume_aligned(&px[fb +  4], 16), 16);
        __builtin_memcpy(&q10, __builtin_assume_aligned(&px[fb +  8], 16), 16);
        __builtin_memcpy(&q11, __builtin_assume_aligned(&px[fb + 12], 16), 16);
        const float bv0 = bias[obase + l16];
        const float bv1 = bias[obase + 16 + l16];
        f32x4 r00 = acc00 + q00 + bv0;
        f32x4 r01 = acc01 + q01 + bv1;
        f32x4 r10 = acc10 + q10 + bv0;
        f32x4 r11 = acc11 + q11 + bv1;
        float* ob = out + ((size_t)n * OO + obase) * TT;
        __builtin_memcpy(__builtin_assume_aligned(ob + (size_t)l16 * TT + quad * 4, 16), &r00, 16);
        __builtin_memcpy(__builtin_assume_aligned(ob + (size_t)(16 + l16) * TT + quad * 4, 16), &r01, 16);
        __builtin_memcpy(__builtin_assume_aligned(ob + (size_t)l16 * TT + 16 + quad * 4, 16), &r10, 16);
        __builtin_memcpy(__builtin_assume_aligned(ob + (size_t)(16 + l16) * TT + 16 + quad * 4, 16), &r11, 16);
    }
}

// ---------- fallback (ws too small): fp32 path, LDS kern (proven) ----------
__global__ __launch_bounds__(256, 2)
void iconv_ref(const float* __restrict__ pept,
               const float* __restrict__ mhc,
               const float* __restrict__ wgt,
               const float* __restrict__ bias,
               float* __restrict__ out)
{
    __shared__ __align__(16) u16 s_mem[PEPT_U16 + 4 * KS_U16];
    const int tid  = threadIdx.x;
    const int wave = tid >> 6;
    const int dh   = wave & 1;
    const int lane = tid & 63;
    const int quad = lane >> 4;
    const int l16  = lane & 15;
    const int n  = blockIdx.x >> 2;
    const int oq = blockIdx.x & 3;
    const int obase = (oq * 2 + (wave >> 1)) * 32;
    u16* const s_pept = s_mem;
    u16* const ks     = s_mem + PEPT_U16 + wave * KS_U16;

    auto loadW = [&](int o_base, int k, bf16x8 wF[2][2]) {
        #pragma unroll
        for (int mt = 0; mt < 2; ++mt) {
            const float* wrow = wgt + ((size_t)(o_base + mt * 16 + l16) * KK + k) * MHCL;
            float w8[8];
            __builtin_memcpy(w8, __builtin_assume_aligned(wrow + quad * 8, 8), 32);
            u16 h0[8];
            #pragma unroll
            for (int j = 0; j < 8; ++j) h0[j] = f2bf(w8[j]);
            __builtin_memcpy(&wF[mt][0], h0, 16);
            u16 h1[8] = {0,0,0,0,0,0,0,0};
            if (quad == 0) { h1[0] = f2bf(wrow[32]); h1[1] = f2bf(wrow[33]); }
            __builtin_memcpy(&wF[mt][1], h1, 16);
        }
    };

    bf16x8 wB[2][2];
    loadW(obase, 0, wB);

    bf16x8 mA[4][2];
    {
        const float* mg = mhc + (size_t)n * MHCL * DD;
        #pragma unroll
        for (int di = 0; di < 4; ++di) {
            const int d = dh * 64 + di * 16 + l16;
            u16 h0[8];
            #pragma unroll
            for (int j = 0; j < 8; ++j)
                h0[j] = f2bf(mg[(size_t)(quad * 8 + j) * DD + d]);
            __builtin_memcpy(&mA[di][0], h0, 16);
            u16 h1[8] = {0,0,0,0,0,0,0,0};
            if (quad == 0) {
                h1[0] = f2bf(mg[(size_t)32 * DD + d]);
                h1[1] = f2bf(mg[(size_t)33 * DD + d]);
            }
            __builtin_memcpy(&mA[di][1], h1, 16);
        }
    }

    {
        const float* pg = pept + (size_t)n * LL * DD;
        #pragma unroll 1
        for (int i = tid; i < (LL * DD) / 4; i += 256) {
            int row = i >> 5, c4 = (i & 31) << 2;
            f32x4 v;
            __builtin_memcpy(&v, __builtin_assume_aligned(pg + row * DD + c4, 16), 16);
            u32x2 h = { pk2(v[0], v[1]), pk2(v[2], v[3]) };
            __builtin_memcpy(__builtin_assume_aligned(&s_pept[row * PSTR + c4], 8), &h, 8);
        }
    }
    __syncthreads();

    f32x4 acc00 = {0.f,0.f,0.f,0.f}, acc01 = acc00, acc10 = acc00, acc11 = acc00;

    #pragma unroll 3
    for (int k = 0; k < KK; ++k) {
        #pragma unroll
        for (int di = 0; di < 4; ++di) {
            f32x4 c0 = {0.f,0.f,0.f,0.f}, c1 = c0;
            c0 = mfma16(mA[di][0], wB[0][0], c0);
            c0 = mfma16(mA[di][1], wB[0][1], c0);
            c1 = mfma16(mA[di][0], wB[1][0], c1);
            c1 = mfma16(mA[di][1], wB[1][1], c1);
            u32x2 p0 = { pk2(fmaxf(c0[0], 0.f), fmaxf(c0[1], 0.f)),
                         pk2(fmaxf(c0[2], 0.f), fmaxf(c0[3], 0.f)) };
            u32x2 p1 = { pk2(fmaxf(c1[0], 0.f), fmaxf(c1[1], 0.f)),
                         pk2(fmaxf(c1[2], 0.f), fmaxf(c1[3], 0.f)) };
            __builtin_memcpy(__builtin_assume_aligned(&ks[l16 * KDSTR + di * 16 + quad * 4], 8), &p0, 8);
            __builtin_memcpy(__builtin_assume_aligned(&ks[(16 + l16) * KDSTR + di * 16 + quad * 4], 8), &p1, 8);
        }
        if (k < KK - 1) loadW(obase, k + 1, wB);
        #pragma unroll
        for (int ds = 0; ds < 2; ++ds) {
            bf16x8 kb0 = ld8(&ks[l16 * KDSTR + ds * 32 + quad * 8]);
            bf16x8 kb1 = ld8(&ks[(16 + l16) * KDSTR + ds * 32 + quad * 8]);
            bf16x8 ap0 = ld8(&s_pept[(k + l16) * PSTR + dh * 64 + ds * 32 + quad * 8]);
            bf16x8 ap1 = ld8(&s_pept[(k + 16 + l16) * PSTR + dh * 64 + ds * 32 + quad * 8]);
            acc00 = mfma16(ap0, kb0, acc00);
            acc01 = mfma16(ap0, kb1, acc01);
            acc10 = mfma16(ap1, kb0, acc10);
            acc11 = mfma16(ap1, kb1, acc11);
        }
    }

    if (dh == 1) {
        float* ox = (float*)ks;
        const int fb = lane * 16;
        __builtin_memcpy(__builtin_assume_aligned(&ox[fb +  0], 16), &acc00, 16);
        __builtin_memcpy(__builtin_assume_aligned(&ox[fb +  4], 16), &acc01, 16);
        __builtin_memcpy(__builtin_assume_aligned(&ox[fb +  8], 16), &acc10, 16);
        __builtin_memcpy(__builtin_assume_aligned(&ox[fb + 12], 16), &acc11, 16);
    }
    __syncthreads();
    if (dh == 0) {
        const float* px = (const float*)(s_mem + PEPT_U16 + (wave + 1) * KS_U16);
        const int fb = lane * 16;
        f32x4 q00, q01, q10, q11;
        __builtin_memcpy(&q00, __builtin_assume_aligned(&px[fb +  0], 16), 16);
        __builtin_memcpy(&q01, __builtin_assume_aligned(&px[fb +  4], 16), 16);
        __builtin_memcpy(&q10, __builtin_assume_aligned(&px[fb +  8], 16), 16);
        __builtin_memcpy(&q11, __builtin_assume_aligned(&px[fb + 12], 16), 16);
        const float bv0 = bias[obase + l16];
        const float bv1 = bias[obase + 16 + l16];
        f32x4 r00 = acc00 + q00 + bv0;
        f32x4 r01 = acc01 + q01 + bv1;
        f32x4 r10 = acc10 + q10 + bv0;
        f32x4 r11 = acc11 + q11 + bv1;
        float* ob = out + ((size_t)n * OO + obase) * TT;
        __builtin_memcpy(__builtin_assume_aligned(ob + (size_t)l16 * TT + quad * 4, 16), &r00, 16);
        __builtin_memcpy(__builtin_assume_aligned(ob + (size_t)(16 + l16) * TT + quad * 4, 16), &r01, 16);
        __builtin_memcpy(__builtin_assume_aligned(ob + (size_t)l16 * TT + 16 + quad * 4, 16), &r10, 16);
        __builtin_memcpy(__builtin_assume_aligned(ob + (size_t)(16 + l16) * TT + 16 + quad * 4, 16), &r11, 16);
    }
}

extern "C" void kernel_launch(void* const* d_in, const int* in_sizes, int n_in,
                              void* d_out, int out_size, void* d_ws, size_t ws_size,
                              hipStream_t stream) {
    const float* pept = (const float*)d_in[0];
    const float* mhc  = (const float*)d_in[1];
    const float* wgt  = (const float*)d_in[2];
    const float* bias = (const float*)d_in[3];
    float* out = (float*)d_out;

    const size_t w_bytes = (size_t)OO * KK * WPADL * sizeof(u16);   // 294,912
    const size_t p_bytes = (size_t)NN * LL * DD * sizeof(u16);      // 5,242,880
    if (ws_size >= w_bytes + p_bytes) {
        u16* wp = (u16*)d_ws;
        u16* pp = (u16*)((char*)d_ws + w_bytes);
        const int total = OO * KK * (WPADL / 2) + NN * LL * DD / 2;  // 1,347,584
        cvt_all<<<dim3((total + 255) / 256), dim3(256), 0, stream>>>(wgt, pept, (u32*)wp, (u32*)pp);
        iconv_fast<<<dim3(NN * 4), dim3(256), 0, stream>>>(mhc, wp, pp, bias, out);
    } else {
        iconv_ref<<<dim3(NN * 4), dim3(256), 0, stream>>>(pept, mhc, wgt, bias, out);
    }
}